// Round 3
// baseline (279.510 us; speedup 1.0000x reference)
//
#include <hip/hip_runtime.h>

// BilinearSampler: img [B,H,W,C] f32, x_s/y_s [B,H,W] f32 in [-1,1] -> out [B,H,W,C] f32
// B=16, H=256, W=256, C=32.
// Mapping: 8 threads per pixel, each thread handles one float4 channel group.
// Wave of 64 lanes = 8 consecutive pixels * full C -> coalesced 1 KiB store.
// R3: 4 pixel-groups per thread, software-pipelined (16 gather loads in flight).
// R4 (REVERTED): XCD swizzle cut FETCH 221->157 MB but regressed 88->105 us.
//     => HBM bytes are NOT the limiter.
// R5 (REVERTED): sched_barrier-forced MLP. VGPR 36->56, occupancy 68->39%,
//     dur unchanged 88.5->89.5. => latency-hiding/MLP is NOT the limiter;
//     outstanding-bytes per CU varied ~2x across R3/R5 with no effect.
// R6: theory = per-CU L1 request-path service wall (MSHR/miss-alloc slots).
//     Demand traffic is 12.5 B/cyc/CU (> streaming copy's ~10), gathers are
//     uniform-random with ~0% L1 hit rate, yet every gather pays L1
//     lookup+allocate+miss-track. Mark img gathers nontemporal to stream
//     past L1 allocation. Predict: dur 88 -> ~70-75 us if L1-path-bound;
//     unchanged if the wall is the downstream random-access service rate.

constexpr int Bn = 16;
constexpr int Hn = 256;
constexpr int Wn = 256;
constexpr int Cn = 32;
constexpr int CG = Cn / 4;   // 8 float4 groups per pixel
constexpr int NP = 4;        // pixel-groups per thread

typedef float f4 __attribute__((ext_vector_type(4)));

__global__ __launch_bounds__(256) void bilinear_kernel(
    const float* __restrict__ img,
    const float* __restrict__ xs,
    const float* __restrict__ ys,
    float* __restrict__ out)
{
    const int tid = threadIdx.x;
    const int cg  = tid & 7;          // channel group (float4 index)
    const int lp  = tid >> 3;         // local pixel 0..31
    // block covers 128 consecutive pixels as 4 chunks of 32
    const int base_pix = blockIdx.x * 128 + lp;

    int pix[NP];
    float xsv[NP], ysv[NP];
#pragma unroll
    for (int g = 0; g < NP; ++g) {
        pix[g] = base_pix + g * 32;
        xsv[g] = __builtin_nontemporal_load(xs + pix[g]);
        ysv[g] = __builtin_nontemporal_load(ys + pix[g]);
    }

    float wa[NP], wb[NP], wc[NP], wd[NP];
    const f4* pa[NP];
    const f4* pb[NP];
    const f4* pc[NP];
    const f4* pd[NP];

#pragma unroll
    for (int g = 0; g < NP; ++g) {
        const float x = 0.5f * (xsv[g] + 1.0f) * (float)(Wn - 1);
        const float y = 0.5f * (ysv[g] + 1.0f) * (float)(Hn - 1);

        const int x0 = (int)floorf(x);
        const int y0 = (int)floorf(y);

        const int x0c = min(max(x0, 0), Wn - 1);
        const int x1c = min(max(x0 + 1, 0), Wn - 1);
        const int y0c = min(max(y0, 0), Hn - 1);
        const int y1c = min(max(y0 + 1, 0), Hn - 1);

        const float wx1 = (float)x1c - x;
        const float wx0 = x - (float)x0c;
        const float wy1 = (float)y1c - y;
        const float wy0 = y - (float)y0c;

        wa[g] = wx1 * wy1;
        wb[g] = wx1 * wy0;
        wc[g] = wx0 * wy1;
        wd[g] = wx0 * wy0;

        const int b = pix[g] >> 16;  // H*W = 65536
        const size_t imgbase = (size_t)b * (size_t)(Hn * Wn * Cn);

        pa[g] = (const f4*)(img + imgbase + ((size_t)(y0c * Wn + x0c)) * Cn) + cg;
        pb[g] = (const f4*)(img + imgbase + ((size_t)(y1c * Wn + x0c)) * Cn) + cg;
        pc[g] = (const f4*)(img + imgbase + ((size_t)(y0c * Wn + x1c)) * Cn) + cg;
        pd[g] = (const f4*)(img + imgbase + ((size_t)(y1c * Wn + x1c)) * Cn) + cg;
    }

    // issue all 16 gather loads before consuming any; nontemporal = don't
    // allocate in L1 (hit rate ~0 for uniform-random gathers anyway).
    f4 va[NP], vb[NP], vc[NP], vd[NP];
#pragma unroll
    for (int g = 0; g < NP; ++g) {
        va[g] = __builtin_nontemporal_load(pa[g]);
        vb[g] = __builtin_nontemporal_load(pb[g]);
        vc[g] = __builtin_nontemporal_load(pc[g]);
        vd[g] = __builtin_nontemporal_load(pd[g]);
    }

#pragma unroll
    for (int g = 0; g < NP; ++g) {
        f4 o;
        o.x = wa[g] * va[g].x + wb[g] * vb[g].x + wc[g] * vc[g].x + wd[g] * vd[g].x;
        o.y = wa[g] * va[g].y + wb[g] * vb[g].y + wc[g] * vc[g].y + wd[g] * vd[g].y;
        o.z = wa[g] * va[g].z + wb[g] * vb[g].z + wc[g] * vc[g].z + wd[g] * vd[g].z;
        o.w = wa[g] * va[g].w + wb[g] * vb[g].w + wc[g] * vc[g].w + wd[g] * vd[g].w;

        f4* op = (f4*)out + (size_t)pix[g] * CG + cg;
        __builtin_nontemporal_store(o, op);
    }
}

extern "C" void kernel_launch(void* const* d_in, const int* in_sizes, int n_in,
                              void* d_out, int out_size, void* d_ws, size_t ws_size,
                              hipStream_t stream)
{
    const float* img = (const float*)d_in[0];
    const float* xs  = (const float*)d_in[1];
    const float* ys  = (const float*)d_in[2];
    float* out       = (float*)d_out;

    const int total_pixels = Bn * Hn * Wn;        // 1,048,576
    const int block = 256;
    const int grid  = total_pixels / 128;         // 8192 blocks, 128 px/block

    bilinear_kernel<<<grid, block, 0, stream>>>(img, xs, ys, out);
}